// Round 1
// baseline (611.785 us; speedup 1.0000x reference)
//
#include <hip/hip_runtime.h>

// LinkPrediction: per-edge 2-layer MLP routed by edge type (MoE-style).
// outputs: [0..N_EDGES) = scores, [N_EDGES..) = copy of rgcn_emb.

constexpr int N_NODES = 200000;
constexpr int N_EDGES = 400000;
constexpr int EMB_DIM = 128;
constexpr int HID     = 24;
constexpr int N_TYPES = 8;
constexpr int BLK     = 256;

// counting-sort buckets padded to BLK multiples
constexpr int MAX_PAD      = N_EDGES + N_TYPES * (BLK - 1);           // worst-case padded slots
constexpr int SCORE_BLOCKS = (MAX_PAD + BLK - 1) / BLK;
constexpr int COPY_BLOCKS  = 4096;

// ws layout (ints): [0..8) counts, [8..16) fill, [16..25) poff, [32..32+MAX_PAD) sorted
__global__ void init_k(int* __restrict__ w) {
    if (threadIdx.x < 32) w[threadIdx.x] = 0;
}

__global__ void hist_k(const int* __restrict__ etype, int* __restrict__ counts) {
    __shared__ int lc[N_TYPES];
    if (threadIdx.x < N_TYPES) lc[threadIdx.x] = 0;
    __syncthreads();
    int e = blockIdx.x * BLK + threadIdx.x;
    if (e < N_EDGES) atomicAdd(&lc[etype[e]], 1);
    __syncthreads();
    if (threadIdx.x < N_TYPES && lc[threadIdx.x]) atomicAdd(&counts[threadIdx.x], lc[threadIdx.x]);
}

__global__ void offsets_k(const int* __restrict__ counts, int* __restrict__ poff) {
    // single thread: 8 buckets, pad each to a BLK multiple
    int off = 0;
    for (int t = 0; t < N_TYPES; ++t) {
        poff[t] = off;
        off += ((counts[t] + BLK - 1) / BLK) * BLK;
    }
    poff[N_TYPES] = off;
}

__global__ void scatter_k(const int* __restrict__ etype, const int* __restrict__ poff,
                          int* __restrict__ fill, int* __restrict__ sorted) {
    __shared__ int lc[N_TYPES], lb[N_TYPES];
    if (threadIdx.x < N_TYPES) lc[threadIdx.x] = 0;
    __syncthreads();
    int e = blockIdx.x * BLK + threadIdx.x;
    int t = 0, r = 0;
    bool ok = (e < N_EDGES);
    if (ok) { t = etype[e]; r = atomicAdd(&lc[t], 1); }
    __syncthreads();
    if (threadIdx.x < N_TYPES) lb[threadIdx.x] = atomicAdd(&fill[threadIdx.x], lc[threadIdx.x]);
    __syncthreads();
    if (ok) sorted[poff[t] + lb[t] + r] = e;
}

__device__ __forceinline__ void accum_half(const float4* __restrict__ x,
                                           const float* __restrict__ w0,
                                           float acc[HID]) {
    for (int i = 0; i < EMB_DIM / 4; ++i) {
        float4 v = x[i];
        const float* w = w0 + i * 4 * HID;
#pragma unroll
        for (int j = 0; j < HID; ++j) acc[j] = fmaf(v.x, w[0 * HID + j], acc[j]);
#pragma unroll
        for (int j = 0; j < HID; ++j) acc[j] = fmaf(v.y, w[1 * HID + j], acc[j]);
#pragma unroll
        for (int j = 0; j < HID; ++j) acc[j] = fmaf(v.z, w[2 * HID + j], acc[j]);
#pragma unroll
        for (int j = 0; j < HID; ++j) acc[j] = fmaf(v.w, w[3 * HID + j], acc[j]);
    }
}

__device__ __forceinline__ void score_edge(int e, int t,
        const float* __restrict__ emb,
        const int* __restrict__ srci, const int* __restrict__ dsti,
        const float* __restrict__ W1, const float* __restrict__ b1,
        const float* __restrict__ W2, const float* __restrict__ b2,
        float* __restrict__ out) {
    float acc[HID];
#pragma unroll
    for (int j = 0; j < HID; ++j) acc[j] = b1[t * HID + j];
    const float* W1t = W1 + (size_t)t * (2 * EMB_DIM * HID);
    int s = srci[e], d = dsti[e];
    accum_half((const float4*)(emb + (size_t)s * EMB_DIM), W1t, acc);
    accum_half((const float4*)(emb + (size_t)d * EMB_DIM), W1t + EMB_DIM * HID, acc);
    float sc = b2[t];
#pragma unroll
    for (int j = 0; j < HID; ++j) {
        float h = acc[j];
        h = (h > 0.f) ? h : 0.01f * h;       // LeakyReLU(0.01)
        sc = fmaf(h, W2[t * HID + j], sc);
    }
    out[e] = sc;
}

__device__ __forceinline__ void do_copy(const float* __restrict__ emb,
                                        float* __restrict__ out, int cb, int nb) {
    const float4* s4 = (const float4*)emb;
    float4* o4 = (float4*)(out + N_EDGES);
    const long long n4 = (long long)N_NODES * EMB_DIM / 4;
    long long stride = (long long)nb * BLK;
    for (long long i = (long long)cb * BLK + threadIdx.x; i < n4; i += stride)
        o4[i] = s4[i];
}

__global__ __launch_bounds__(BLK) void main_sorted(
        const float* __restrict__ emb,
        const int* __restrict__ srci, const int* __restrict__ dsti,
        const int* __restrict__ counts, const int* __restrict__ poff,
        const int* __restrict__ sorted,
        const float* __restrict__ W1, const float* __restrict__ b1,
        const float* __restrict__ W2, const float* __restrict__ b2,
        float* __restrict__ out) {
    int b = blockIdx.x;
    if (b >= SCORE_BLOCKS) {
        do_copy(emb, out, b - SCORE_BLOCKS, (int)gridDim.x - SCORE_BLOCKS);
        return;
    }
    int slot0 = b * BLK;
    if (slot0 >= poff[N_TYPES]) return;
    // bucket id (block-uniform: bucket boundaries are BLK multiples)
    int t = 0;
#pragma unroll
    for (int i = 1; i < N_TYPES; ++i)
        if (slot0 >= poff[i]) t = i;
    t = __builtin_amdgcn_readfirstlane(t);   // force scalar-uniform type
    int cnt = counts[t];
    int local = slot0 - poff[t] + (int)threadIdx.x;
    if (local < cnt) {
        int e = sorted[slot0 + threadIdx.x];
        score_edge(e, t, emb, srci, dsti, W1, b1, W2, b2, out);
    }
}

__global__ __launch_bounds__(BLK) void main_unsorted(
        const float* __restrict__ emb,
        const int* __restrict__ srci, const int* __restrict__ dsti,
        const int* __restrict__ etype,
        const float* __restrict__ W1, const float* __restrict__ b1,
        const float* __restrict__ W2, const float* __restrict__ b2,
        float* __restrict__ out) {
    constexpr int EB = (N_EDGES + BLK - 1) / BLK;
    int b = blockIdx.x;
    if (b >= EB) {
        do_copy(emb, out, b - EB, (int)gridDim.x - EB);
        return;
    }
    int e = b * BLK + threadIdx.x;
    if (e < N_EDGES) {
        int t = etype[e];
        score_edge(e, t, emb, srci, dsti, W1, b1, W2, b2, out);
    }
}

extern "C" void kernel_launch(void* const* d_in, const int* in_sizes, int n_in,
                              void* d_out, int out_size, void* d_ws, size_t ws_size,
                              hipStream_t stream) {
    const float* emb   = (const float*)d_in[0];
    const int*   eidx  = (const int*)d_in[1];
    const int*   etype = (const int*)d_in[2];
    const float* W1    = (const float*)d_in[3];
    const float* b1    = (const float*)d_in[4];
    const float* W2    = (const float*)d_in[5];
    const float* b2    = (const float*)d_in[6];
    float* out = (float*)d_out;
    const int* srci = eidx;
    const int* dsti = eidx + N_EDGES;

    size_t need = (size_t)(32 + MAX_PAD) * sizeof(int);
    if (ws_size >= need) {
        int* counts = (int*)d_ws;
        int* poff   = counts + 16;
        int* fill   = counts + 8;
        int* sorted = counts + 32;
        init_k<<<1, 64, 0, stream>>>(counts);
        hist_k<<<(N_EDGES + BLK - 1) / BLK, BLK, 0, stream>>>(etype, counts);
        offsets_k<<<1, 1, 0, stream>>>(counts, poff);
        scatter_k<<<(N_EDGES + BLK - 1) / BLK, BLK, 0, stream>>>(etype, poff, fill, sorted);
        main_sorted<<<SCORE_BLOCKS + COPY_BLOCKS, BLK, 0, stream>>>(
            emb, srci, dsti, counts, poff, sorted, W1, b1, W2, b2, out);
    } else {
        constexpr int EB = (N_EDGES + BLK - 1) / BLK;
        main_unsorted<<<EB + COPY_BLOCKS, BLK, 0, stream>>>(
            emb, srci, dsti, etype, W1, b1, W2, b2, out);
    }
}

// Round 2
// 290.976 us; speedup vs baseline: 2.1025x; 2.1025x over previous
//
#include <hip/hip_runtime.h>

// LinkPrediction: per-edge 2-layer MLP routed by edge type (MoE-style).
// outputs: [0..N_EDGES) = scores, [N_EDGES..) = copy of rgcn_emb.
//
// R1 analysis: FETCH_SIZE 1.27GB vs ~0.52GB ideal (2.4x refetch from L1 thrash:
// 16B consumed per 768 VALU instrs while 4-8 waves x 64 random rows thrash L1).
// R2: burst-load rows in 128B (one-cache-line) register chunks -> each line
// fetched once. Also: fold init/offsets into memsetAsync + local prefix.

constexpr int N_NODES = 200000;
constexpr int N_EDGES = 400000;
constexpr int EMB_DIM = 128;
constexpr int HID     = 24;
constexpr int N_TYPES = 8;
constexpr int BLK     = 256;

constexpr int MAX_PAD      = N_EDGES + N_TYPES * (BLK - 1);
constexpr int SCORE_BLOCKS = (MAX_PAD + BLK - 1) / BLK;
constexpr int COPY_BLOCKS  = 2048;

// ws layout (ints): [0..8) counts, [8..16) fill, [16..16+MAX_PAD) sorted

__global__ void hist_k(const int* __restrict__ etype, int* __restrict__ counts) {
    __shared__ int lc[N_TYPES];
    if (threadIdx.x < N_TYPES) lc[threadIdx.x] = 0;
    __syncthreads();
    int e = blockIdx.x * BLK + threadIdx.x;
    if (e < N_EDGES) atomicAdd(&lc[etype[e]], 1);
    __syncthreads();
    if (threadIdx.x < N_TYPES && lc[threadIdx.x]) atomicAdd(&counts[threadIdx.x], lc[threadIdx.x]);
}

__global__ void scatter_k(const int* __restrict__ etype, int* __restrict__ counts,
                          int* __restrict__ sorted) {
    __shared__ int lc[N_TYPES], lb[N_TYPES], spoff[N_TYPES];
    if (threadIdx.x == 0) {
        int off = 0;
        for (int t = 0; t < N_TYPES; ++t) {
            spoff[t] = off;
            off += ((counts[t] + BLK - 1) / BLK) * BLK;
        }
    }
    if (threadIdx.x < N_TYPES) lc[threadIdx.x] = 0;
    __syncthreads();
    int e = blockIdx.x * BLK + threadIdx.x;
    int t = 0, r = 0;
    bool ok = (e < N_EDGES);
    if (ok) { t = etype[e]; r = atomicAdd(&lc[t], 1); }
    __syncthreads();
    if (threadIdx.x < N_TYPES) lb[threadIdx.x] = atomicAdd(&counts[8 + threadIdx.x], lc[threadIdx.x]);
    __syncthreads();
    if (ok) sorted[spoff[t] + lb[t] + r] = e;
}

// One half (128 floats) of the concat row: burst-load 128B chunks (exactly one
// cache line) into registers back-to-back, then consume. Each HBM line is
// fetched once (MSHR-merged), never re-fetched.
__device__ __forceinline__ void half_mm(const float4* __restrict__ x4,
                                        const float* __restrict__ w,  // [128][HID]
                                        float acc[HID]) {
#pragma unroll 1
    for (int c = 0; c < 4; ++c) {           // 4 chunks x 128B
        float4 r[8];
#pragma unroll
        for (int k = 0; k < 8; ++k) r[k] = x4[c * 8 + k];
#pragma unroll
        for (int k = 0; k < 8; ++k) {
            const float* wp = w + (c * 32 + k * 4) * HID;
#pragma unroll
            for (int j = 0; j < HID; ++j) acc[j] = fmaf(r[k].x, wp[0 * HID + j], acc[j]);
#pragma unroll
            for (int j = 0; j < HID; ++j) acc[j] = fmaf(r[k].y, wp[1 * HID + j], acc[j]);
#pragma unroll
            for (int j = 0; j < HID; ++j) acc[j] = fmaf(r[k].z, wp[2 * HID + j], acc[j]);
#pragma unroll
            for (int j = 0; j < HID; ++j) acc[j] = fmaf(r[k].w, wp[3 * HID + j], acc[j]);
        }
    }
}

__device__ __forceinline__ void score_edge(int e, int t,
        const float* __restrict__ emb,
        const int* __restrict__ srci, const int* __restrict__ dsti,
        const float* __restrict__ W1, const float* __restrict__ b1,
        const float* __restrict__ W2, const float* __restrict__ b2,
        float* __restrict__ out) {
    float acc[HID];
#pragma unroll
    for (int j = 0; j < HID; ++j) acc[j] = b1[t * HID + j];
    const float* W1t = W1 + (size_t)t * (2 * EMB_DIM * HID);
    int s = srci[e], d = dsti[e];
    half_mm((const float4*)(emb + (size_t)s * EMB_DIM), W1t, acc);
    half_mm((const float4*)(emb + (size_t)d * EMB_DIM), W1t + EMB_DIM * HID, acc);
    float sc = b2[t];
#pragma unroll
    for (int j = 0; j < HID; ++j) {
        float h = acc[j];
        h = (h > 0.f) ? h : 0.01f * h;       // LeakyReLU(0.01)
        sc = fmaf(h, W2[t * HID + j], sc);
    }
    out[e] = sc;
}

__device__ __forceinline__ void do_copy(const float* __restrict__ emb,
                                        float* __restrict__ out, int cb, int nb) {
    const float4* s4 = (const float4*)emb;
    float4* o4 = (float4*)(out + N_EDGES);
    const long long n4 = (long long)N_NODES * EMB_DIM / 4;
    long long stride = (long long)nb * BLK;
    for (long long i = (long long)cb * BLK + threadIdx.x; i < n4; i += stride)
        o4[i] = s4[i];
}

__global__ __launch_bounds__(BLK) void main_sorted(
        const float* __restrict__ emb,
        const int* __restrict__ srci, const int* __restrict__ dsti,
        const int* __restrict__ counts, const int* __restrict__ sorted,
        const float* __restrict__ W1, const float* __restrict__ b1,
        const float* __restrict__ W2, const float* __restrict__ b2,
        float* __restrict__ out) {
    int b = blockIdx.x;
    if (b >= SCORE_BLOCKS) {
        do_copy(emb, out, b - SCORE_BLOCKS, (int)gridDim.x - SCORE_BLOCKS);
        return;
    }
    // local padded prefix over 8 buckets (scalar-uniform)
    int poff[N_TYPES];
    int off = 0;
#pragma unroll
    for (int t = 0; t < N_TYPES; ++t) {
        poff[t] = off;
        off += ((counts[t] + BLK - 1) / BLK) * BLK;
    }
    int slot0 = b * BLK;
    if (slot0 >= off) return;
    int t = 0;
#pragma unroll
    for (int i = 1; i < N_TYPES; ++i)
        if (slot0 >= poff[i]) t = i;
    t = __builtin_amdgcn_readfirstlane(t);   // wave-uniform type -> scalar W1 base
    int cnt = counts[t];
    int local = slot0 - poff[t] + (int)threadIdx.x;
    if (local < cnt) {
        int e = sorted[slot0 + threadIdx.x];
        score_edge(e, t, emb, srci, dsti, W1, b1, W2, b2, out);
    }
}

__global__ __launch_bounds__(BLK) void main_unsorted(
        const float* __restrict__ emb,
        const int* __restrict__ srci, const int* __restrict__ dsti,
        const int* __restrict__ etype,
        const float* __restrict__ W1, const float* __restrict__ b1,
        const float* __restrict__ W2, const float* __restrict__ b2,
        float* __restrict__ out) {
    constexpr int EB = (N_EDGES + BLK - 1) / BLK;
    int b = blockIdx.x;
    if (b >= EB) {
        do_copy(emb, out, b - EB, (int)gridDim.x - EB);
        return;
    }
    int e = b * BLK + threadIdx.x;
    if (e < N_EDGES) {
        int t = etype[e];
        score_edge(e, t, emb, srci, dsti, W1, b1, W2, b2, out);
    }
}

extern "C" void kernel_launch(void* const* d_in, const int* in_sizes, int n_in,
                              void* d_out, int out_size, void* d_ws, size_t ws_size,
                              hipStream_t stream) {
    const float* emb   = (const float*)d_in[0];
    const int*   eidx  = (const int*)d_in[1];
    const int*   etype = (const int*)d_in[2];
    const float* W1    = (const float*)d_in[3];
    const float* b1    = (const float*)d_in[4];
    const float* W2    = (const float*)d_in[5];
    const float* b2    = (const float*)d_in[6];
    float* out = (float*)d_out;
    const int* srci = eidx;
    const int* dsti = eidx + N_EDGES;

    size_t need = (size_t)(16 + MAX_PAD) * sizeof(int);
    if (ws_size >= need) {
        int* counts = (int*)d_ws;           // [0..8) counts, [8..16) fill
        int* sorted = counts + 16;
        hipMemsetAsync(counts, 0, 16 * sizeof(int), stream);
        hist_k<<<(N_EDGES + BLK - 1) / BLK, BLK, 0, stream>>>(etype, counts);
        scatter_k<<<(N_EDGES + BLK - 1) / BLK, BLK, 0, stream>>>(etype, counts, sorted);
        main_sorted<<<SCORE_BLOCKS + COPY_BLOCKS, BLK, 0, stream>>>(
            emb, srci, dsti, counts, sorted, W1, b1, W2, b2, out);
    } else {
        constexpr int EB = (N_EDGES + BLK - 1) / BLK;
        main_unsorted<<<EB + COPY_BLOCKS, BLK, 0, stream>>>(
            emb, srci, dsti, etype, W1, b1, W2, b2, out);
    }
}

// Round 3
// 278.366 us; speedup vs baseline: 2.1978x; 1.0453x over previous
//
#include <hip/hip_runtime.h>

// LinkPrediction: per-edge 2-layer MLP routed by edge type (MoE-style).
// outputs: [0..N_EDGES) = scores, [N_EDGES..) = copy of rgcn_emb.
//
// R2 post-mortem: main_sorted 116us but TOTAL 291us -> ~170us in hist/scatter
// (12.5K device-scope atomics on 8 addresses, serialized). Score kernel is
// latency/TA-bound (VALUBusy 29%, HBM 40%).
// R3: (1) low-contention hist + two-pass reservation scatter (1K atomics);
//     (2) f16 emb+W1 (stream-converted) + v_dot2_f32_f16 -> halves gather
//     bytes, divergent line fetches, and VALU work. fp32 accumulate.

typedef _Float16 h2 __attribute__((ext_vector_type(2)));

constexpr int N_NODES = 200000;
constexpr int N_EDGES = 400000;
constexpr int EMB_DIM = 128;
constexpr int HID     = 24;
constexpr int N_TYPES = 8;
constexpr int BLK     = 256;

constexpr int MAX_PAD      = N_EDGES + N_TYPES * (BLK - 1);
constexpr int SCORE_BLOCKS = (MAX_PAD + BLK - 1) / BLK;
constexpr int COPY_BLOCKS  = 1024;
constexpr int HIST_BLOCKS  = 128;
constexpr int SC_BLOCKS    = 128;
constexpr int SC_CH        = (N_EDGES + SC_BLOCKS - 1) / SC_BLOCKS;  // 3125
constexpr int CV_BLOCKS    = 1536;

// ws layout: [0..8) counts, [8..16) fill, [16..16+MAX_PAD) sorted,
// then (256B-aligned) emb16 (N_NODES*128 f16 = 51.2MB), then w16 (98.3KB).
constexpr size_t SORT_BYTES = (size_t)(16 + MAX_PAD) * sizeof(int);
constexpr size_t EMB16_OFF  = (SORT_BYTES + 255) & ~(size_t)255;
constexpr size_t EMB16_BYTES = (size_t)N_NODES * EMB_DIM * 2;
constexpr size_t W16_OFF    = EMB16_OFF + EMB16_BYTES;
constexpr size_t W16_BYTES  = (size_t)N_TYPES * 128 * HID * 4;  // h2 per (kp,j)
constexpr size_t NEED16     = W16_OFF + W16_BYTES;

__device__ __forceinline__ float fdot2f(h2 a, h2 b, float c) {
#if __has_builtin(__builtin_amdgcn_fdot2)
    return __builtin_amdgcn_fdot2(a, b, c, false);
#else
    return c + (float)a[0] * (float)b[0] + (float)a[1] * (float)b[1];
#endif
}

// ---------- hist: 128 blocks grid-stride, 8 atomics/block ----------
__global__ __launch_bounds__(BLK) void hist_k(const int* __restrict__ etype,
                                              int* __restrict__ counts) {
    __shared__ int lc[N_TYPES];
    if (threadIdx.x < N_TYPES) lc[threadIdx.x] = 0;
    __syncthreads();
    for (int e = blockIdx.x * BLK + threadIdx.x; e < N_EDGES; e += HIST_BLOCKS * BLK)
        atomicAdd(&lc[etype[e]], 1);
    __syncthreads();
    if (threadIdx.x < N_TYPES) {
        int v = lc[threadIdx.x];
        if (v) atomicAdd(&counts[threadIdx.x], v);
    }
}

// ---------- scatter (two-pass reservation) + f16 convert ----------
__global__ __launch_bounds__(BLK) void scatter_convert_k(
        const int* __restrict__ etype, int* __restrict__ counts,
        int* __restrict__ sorted,
        const float* __restrict__ emb, h2* __restrict__ emb16,
        const float* __restrict__ W1, h2* __restrict__ w16, int do16) {
    int b = blockIdx.x;
    if (b < SC_BLOCKS) {
        __shared__ int lc[N_TYPES], base[N_TYPES];
        if (threadIdx.x < N_TYPES) lc[threadIdx.x] = 0;
        __syncthreads();
        int e0 = b * SC_CH, e1 = min(e0 + SC_CH, N_EDGES);
        for (int e = e0 + threadIdx.x; e < e1; e += BLK)
            atomicAdd(&lc[etype[e]], 1);
        __syncthreads();
        if (threadIdx.x < N_TYPES)
            base[threadIdx.x] = atomicAdd(&counts[8 + threadIdx.x], lc[threadIdx.x]);
        __syncthreads();
        if (threadIdx.x < N_TYPES) lc[threadIdx.x] = 0;
        __syncthreads();
        int poff[N_TYPES];
        int off = 0;
#pragma unroll
        for (int t = 0; t < N_TYPES; ++t) {
            poff[t] = off;
            off += ((counts[t] + BLK - 1) / BLK) * BLK;
        }
        for (int e = e0 + threadIdx.x; e < e1; e += BLK) {
            int t = etype[e];
            int r = atomicAdd(&lc[t], 1);
            sorted[poff[t] + base[t] + r] = e;
        }
    } else if (do16) {
        int cb = b - SC_BLOCKS;
        if (cb < 16) {  // W1 fp32 -> h2 pairs: w16[((t*128+kp)*HID)+j]
            for (int p = cb * BLK + threadIdx.x; p < N_TYPES * 128 * HID; p += 16 * BLK) {
                int t   = p / (128 * HID);
                int rem = p - t * 128 * HID;
                int kp  = rem / HID, j = rem - kp * HID;
                h2 v;
                v[0] = (_Float16)W1[(t * 256 + 2 * kp)     * HID + j];
                v[1] = (_Float16)W1[(t * 256 + 2 * kp + 1) * HID + j];
                w16[p] = v;
            }
        }
        const float4* in4 = (const float4*)emb;
        int4* o16 = (int4*)emb16;
        const int ngrp = N_NODES * EMB_DIM / 8;  // 8 floats -> 16B of f16
        for (int g = cb * BLK + threadIdx.x; g < ngrp; g += CV_BLOCKS * BLK) {
            float4 a = in4[2 * g], c = in4[2 * g + 1];
            union { int4 v; h2 h[4]; } u;
            u.h[0] = h2{(_Float16)a.x, (_Float16)a.y};
            u.h[1] = h2{(_Float16)a.z, (_Float16)a.w};
            u.h[2] = h2{(_Float16)c.x, (_Float16)c.y};
            u.h[3] = h2{(_Float16)c.z, (_Float16)c.w};
            o16[g] = u.v;
        }
    }
}

__device__ __forceinline__ void do_copy(const float* __restrict__ emb,
                                        float* __restrict__ out, int cb, int nb) {
    const float4* s4 = (const float4*)emb;
    float4* o4 = (float4*)(out + N_EDGES);
    const long long n4 = (long long)N_NODES * EMB_DIM / 4;
    long long stride = (long long)nb * BLK;
    for (long long i = (long long)cb * BLK + threadIdx.x; i < n4; i += stride)
        o4[i] = s4[i];
}

// ---------- f16 score: gather 256B/row bursts, dot2 with scalar W1 ----------
__global__ __launch_bounds__(BLK) void score16_k(
        const unsigned short* __restrict__ emb16u, const float* __restrict__ emb,
        const int* __restrict__ srci, const int* __restrict__ dsti,
        const int* __restrict__ counts, const int* __restrict__ sorted,
        const h2* __restrict__ w16, const float* __restrict__ b1,
        const float* __restrict__ W2, const float* __restrict__ b2,
        float* __restrict__ out) {
    int b = blockIdx.x;
    if (b >= SCORE_BLOCKS) {
        do_copy(emb, out, b - SCORE_BLOCKS, (int)gridDim.x - SCORE_BLOCKS);
        return;
    }
    int poff[N_TYPES];
    int off = 0;
#pragma unroll
    for (int t = 0; t < N_TYPES; ++t) {
        poff[t] = off;
        off += ((counts[t] + BLK - 1) / BLK) * BLK;
    }
    int slot0 = b * BLK;
    if (slot0 >= off) return;
    int t = 0;
#pragma unroll
    for (int i = 1; i < N_TYPES; ++i)
        if (slot0 >= poff[i]) t = i;
    t = __builtin_amdgcn_readfirstlane(t);   // wave-uniform type
    int cnt = counts[t];
    int local = slot0 - poff[t] + (int)threadIdx.x;
    if (local >= cnt) return;
    int e = sorted[slot0 + threadIdx.x];
    int s = srci[e], d = dsti[e];

    float acc[HID];
#pragma unroll
    for (int j = 0; j < HID; ++j) acc[j] = b1[t * HID + j];
    const h2* wt = w16 + (size_t)t * 128 * HID;
    const int4* x0 = (const int4*)(emb16u + (size_t)s * EMB_DIM);
    const int4* x1 = (const int4*)(emb16u + (size_t)d * EMB_DIM);

#pragma unroll 1
    for (int half = 0; half < 2; ++half) {
        const int4* xp = half ? x1 : x0;
#pragma unroll 1
        for (int c = 0; c < 2; ++c) {       // 128B (one line) per chunk
            int4 r[8];
#pragma unroll
            for (int k = 0; k < 8; ++k) r[k] = xp[c * 8 + k];
            const h2* hp = (const h2*)r;    // 32 h2 pairs in regs
            const h2* wrow = wt + (half * 64 + c * 32) * HID;
#pragma unroll
            for (int kp = 0; kp < 32; ++kp) {
#pragma unroll
                for (int j = 0; j < HID; ++j)
                    acc[j] = fdot2f(hp[kp], wrow[kp * HID + j], acc[j]);
            }
        }
    }
    float sc = b2[t];
#pragma unroll
    for (int j = 0; j < HID; ++j) {
        float h = acc[j];
        h = (h > 0.f) ? h : 0.01f * h;       // LeakyReLU(0.01)
        sc = fmaf(h, W2[t * HID + j], sc);
    }
    out[e] = sc;
}

// ---------- fp32 score fallback (R2 structure) ----------
__device__ __forceinline__ void half_mm(const float4* __restrict__ x4,
                                        const float* __restrict__ w,
                                        float acc[HID]) {
#pragma unroll 1
    for (int c = 0; c < 4; ++c) {
        float4 r[8];
#pragma unroll
        for (int k = 0; k < 8; ++k) r[k] = x4[c * 8 + k];
#pragma unroll
        for (int k = 0; k < 8; ++k) {
            const float* wp = w + (c * 32 + k * 4) * HID;
#pragma unroll
            for (int j = 0; j < HID; ++j) acc[j] = fmaf(r[k].x, wp[0 * HID + j], acc[j]);
#pragma unroll
            for (int j = 0; j < HID; ++j) acc[j] = fmaf(r[k].y, wp[1 * HID + j], acc[j]);
#pragma unroll
            for (int j = 0; j < HID; ++j) acc[j] = fmaf(r[k].z, wp[2 * HID + j], acc[j]);
#pragma unroll
            for (int j = 0; j < HID; ++j) acc[j] = fmaf(r[k].w, wp[3 * HID + j], acc[j]);
        }
    }
}

__global__ __launch_bounds__(BLK) void score32_k(
        const float* __restrict__ emb,
        const int* __restrict__ srci, const int* __restrict__ dsti,
        const int* __restrict__ counts, const int* __restrict__ sorted,
        const float* __restrict__ W1, const float* __restrict__ b1,
        const float* __restrict__ W2, const float* __restrict__ b2,
        float* __restrict__ out) {
    int b = blockIdx.x;
    if (b >= SCORE_BLOCKS) {
        do_copy(emb, out, b - SCORE_BLOCKS, (int)gridDim.x - SCORE_BLOCKS);
        return;
    }
    int poff[N_TYPES];
    int off = 0;
#pragma unroll
    for (int t = 0; t < N_TYPES; ++t) {
        poff[t] = off;
        off += ((counts[t] + BLK - 1) / BLK) * BLK;
    }
    int slot0 = b * BLK;
    if (slot0 >= off) return;
    int t = 0;
#pragma unroll
    for (int i = 1; i < N_TYPES; ++i)
        if (slot0 >= poff[i]) t = i;
    t = __builtin_amdgcn_readfirstlane(t);
    int cnt = counts[t];
    int local = slot0 - poff[t] + (int)threadIdx.x;
    if (local >= cnt) return;
    int e = sorted[slot0 + threadIdx.x];
    float acc[HID];
#pragma unroll
    for (int j = 0; j < HID; ++j) acc[j] = b1[t * HID + j];
    const float* W1t = W1 + (size_t)t * (2 * EMB_DIM * HID);
    int s = srci[e], d = dsti[e];
    half_mm((const float4*)(emb + (size_t)s * EMB_DIM), W1t, acc);
    half_mm((const float4*)(emb + (size_t)d * EMB_DIM), W1t + EMB_DIM * HID, acc);
    float sc = b2[t];
#pragma unroll
    for (int j = 0; j < HID; ++j) {
        float h = acc[j];
        h = (h > 0.f) ? h : 0.01f * h;
        sc = fmaf(h, W2[t * HID + j], sc);
    }
    out[e] = sc;
}

extern "C" void kernel_launch(void* const* d_in, const int* in_sizes, int n_in,
                              void* d_out, int out_size, void* d_ws, size_t ws_size,
                              hipStream_t stream) {
    const float* emb   = (const float*)d_in[0];
    const int*   eidx  = (const int*)d_in[1];
    const int*   etype = (const int*)d_in[2];
    const float* W1    = (const float*)d_in[3];
    const float* b1    = (const float*)d_in[4];
    const float* W2    = (const float*)d_in[5];
    const float* b2    = (const float*)d_in[6];
    float* out = (float*)d_out;
    const int* srci = eidx;
    const int* dsti = eidx + N_EDGES;

    if (ws_size >= SORT_BYTES) {
        int* counts = (int*)d_ws;            // [0..8) counts, [8..16) fill
        int* sorted = counts + 16;
        bool f16 = (ws_size >= NEED16);
        h2* emb16 = (h2*)((char*)d_ws + EMB16_OFF);
        h2* w16   = (h2*)((char*)d_ws + W16_OFF);
        hipMemsetAsync(counts, 0, 16 * sizeof(int), stream);
        hist_k<<<HIST_BLOCKS, BLK, 0, stream>>>(etype, counts);
        scatter_convert_k<<<SC_BLOCKS + (f16 ? CV_BLOCKS : 0), BLK, 0, stream>>>(
            etype, counts, sorted, emb, emb16, W1, w16, f16 ? 1 : 0);
        if (f16) {
            score16_k<<<SCORE_BLOCKS + COPY_BLOCKS, BLK, 0, stream>>>(
                (const unsigned short*)emb16, emb, srci, dsti, counts, sorted,
                w16, b1, W2, b2, out);
        } else {
            score32_k<<<SCORE_BLOCKS + COPY_BLOCKS, BLK, 0, stream>>>(
                emb, srci, dsti, counts, sorted, W1, b1, W2, b2, out);
        }
    } else {
        // minimal fallback: unsorted (divergent W1) — correctness only
        score32_k<<<SCORE_BLOCKS + COPY_BLOCKS, BLK, 0, stream>>>(
            emb, srci, dsti, nullptr, nullptr, W1, b1, W2, b2, out);
    }
}